// Round 17
// baseline (123.453 us; speedup 1.0000x reference)
//
#include <hip/hip_runtime.h>
#include <cstdint>
#include <climits>

static constexpr int NC    = 2000000;         // clause id range (fixed by reference)
static constexpr int HALF  = 1000000;         // clauses per half-range
static constexpr int NV    = 2000000;         // variables (fixed by reference)
static constexpr int HALFV = 1000000;         // vars per half
static constexpr int NBH   = 128;             // bitmap blocks per clause half
static constexpr int NBLK  = 2 * NBH;         // 256 bitmap blocks (1 per CU)
static constexpr int WPH   = HALF / 32;       // 31,250 words per clause bitmap
static constexpr int WPHV  = HALFV / 32;      // 31,250 words per var bitmap half
static constexpr int LDSW  = 31264;           // LDS alloc words (pad to /4)
static_assert(HALF % 32 == 0 && LDSW % 4 == 0 && LDSW >= WPH && LDSW >= WPHV, "layout");

typedef int   int4v   __attribute__((ext_vector_type(4)));
typedef float float4v __attribute__((ext_vector_type(4)));

// ws layout (bytes). counts[] for the exact path ALIASES the bitmap region
// (bitmaps are dead after reduce_k; stream order serializes the reuse).
static constexpr size_t OFF_BM  = 0;
static constexpr size_t BM_BY   = (size_t)NBLK * LDSW * 4;   // 32,014,336 (64-aligned)
static constexpr size_t OFF_CNT = 0;                          // alias (8 MB)
static constexpr size_t OFF_XBB = BM_BY;                      // bit-packed xb

// Pack xb bits (xb = floor(xv/0.50001f), true f32 divide to match reference),
// init ctrl.
__global__ __launch_bounds__(256) void init_k(const float* __restrict__ xv, int nv,
                                              uint8_t* __restrict__ xbb,
                                              int* __restrict__ ctrl) {
    int stride = gridDim.x * blockDim.x;
    int i0 = blockIdx.x * blockDim.x + threadIdx.x;
    int nbytes = nv >> 3;
    const float4v* p4 = (const float4v*)xv;
    for (int i = i0; i < nbytes; i += stride) {
        float4v a = p4[2 * i], b = p4[2 * i + 1];
        uint32_t m = 0;
        #pragma unroll
        for (int j = 0; j < 4; ++j)
            m |= ((uint32_t)(int)floorf(a[j] / 0.50001f)) << j;
        #pragma unroll
        for (int j = 0; j < 4; ++j)
            m |= ((uint32_t)(int)floorf(b[j] / 0.50001f)) << (4 + j);
        xbb[i] = (uint8_t)m;
    }
    if (i0 == 0) {
        if (nv & 7) {
            uint32_t m = 0;
            for (int j = 0; j < (nv & 7); ++j)
                m |= ((uint32_t)(int)floorf(xv[(nbytes << 3) + j] / 0.50001f)) << j;
            xbb[nbytes] = (uint8_t)m;
        }
        ctrl[0] = 0;        // zero_found
        ctrl[1] = INT_MAX;  // minslot (exact path)
    }
}

// Sat pass with LDS-resident var bitmap. BRANCHLESS gather: clamp the word
// index and ALWAYS ds_read, mask the bit with the in-range predicate via
// plain VALU ops. No exec-mask save/restore -> the ILP streams' gathers are
// freely schedulable (rounds 15/16: predicated gathers serialized through
// exec, making ILP-4 and shfl-removal both null). 4-deep ILP.
// hv=0 overwrites, hv=1 same-thread ORs. Coverage = ne & ~255.
__global__ __launch_bounds__(1024) void satv_k(const int* __restrict__ adj_pos,
                                               const int* __restrict__ adj_neg,
                                               const uint32_t* __restrict__ xbw,
                                               uint8_t* __restrict__ satp,
                                               uint8_t* __restrict__ satn,
                                               int ne_p, int ne_n) {
    __shared__ uint32_t vbm[LDSW];
    const int tid = threadIdx.x;
    const int w0 = blockIdx.x * 1024 + tid;
    const int W = gridDim.x * 1024;          // 262,144 workers

    const int* adjs[2] = {adj_pos, adj_neg};
    uint8_t* sats[2] = {satp, satn};
    int nes[2] = {ne_p, ne_n};

    for (int hv = 0; hv < 2; ++hv) {
        const uint32_t* src = xbw + hv * WPHV;
        for (int j = tid; j < WPHV; j += 1024) vbm[j] = src[j];
        __syncthreads();
        const uint32_t vbase = (uint32_t)(hv * HALFV);

        for (int pol = 0; pol < 2; ++pol) {
            const int ne = nes[pol];
            const int n4c = ((ne & 3) == 0) ? ((ne & ~255) >> 2) : 0;
            const int4v* v4p = (const int4v*)(adjs[pol] + ne);
            uint8_t* sat = sats[pol];

            auto nib = [&](int4v va) -> uint32_t {
                uint32_t n = 0;
                #pragma unroll
                for (int k = 0; k < 4; ++k) {
                    uint32_t u = (uint32_t)va[k] - vbase;
                    uint32_t inr = (u < (uint32_t)HALFV) ? 1u : 0u;
                    uint32_t w = vbm[min(u >> 5, (uint32_t)(WPHV - 1))];
                    uint32_t b = (w >> (u & 31)) & 1u;
                    n |= ((pol ? (b ^ 1u) : b) & inr) << k;
                }
                return n;
            };

            int i = w0;
            if (hv == 0) {
                for (; i + 3 * W < n4c; i += 4 * W) {    // 4-deep ILP
                    int4v v0 = v4p[i], v1 = v4p[i + W];
                    int4v v2 = v4p[i + 2 * W], v3 = v4p[i + 3 * W];
                    uint32_t n0 = nib(v0), n1 = nib(v1);
                    uint32_t n2 = nib(v2), n3 = nib(v3);
                    sat[i] = (uint8_t)n0;           sat[i + W] = (uint8_t)n1;
                    sat[i + 2 * W] = (uint8_t)n2;   sat[i + 3 * W] = (uint8_t)n3;
                }
                for (; i + W < n4c; i += 2 * W) {
                    int4v v0 = v4p[i], v1 = v4p[i + W];
                    uint32_t n0 = nib(v0), n1 = nib(v1);
                    sat[i] = (uint8_t)n0;  sat[i + W] = (uint8_t)n1;
                }
                for (; i < n4c; i += W) sat[i] = (uint8_t)nib(v4p[i]);
            } else {
                for (; i + 3 * W < n4c; i += 4 * W) {
                    int4v v0 = v4p[i], v1 = v4p[i + W];
                    int4v v2 = v4p[i + 2 * W], v3 = v4p[i + 3 * W];
                    uint32_t n0 = nib(v0), n1 = nib(v1);
                    uint32_t n2 = nib(v2), n3 = nib(v3);
                    sat[i] |= (uint8_t)n0;          sat[i + W] |= (uint8_t)n1;
                    sat[i + 2 * W] |= (uint8_t)n2;  sat[i + 3 * W] |= (uint8_t)n3;
                }
                for (; i + W < n4c; i += 2 * W) {
                    int4v v0 = v4p[i], v1 = v4p[i + W];
                    uint32_t n0 = nib(v0), n1 = nib(v1);
                    sat[i] |= (uint8_t)n0;  sat[i + W] |= (uint8_t)n1;
                }
                for (; i < n4c; i += W) sat[i] |= (uint8_t)nib(v4p[i]);
            }
        }
        __syncthreads();   // drain vbm readers before reloading half B
    }
}

// Bitmap pass: block (h,b) owns clause half h and edge share b. W-strided,
// lane-coalesced int4 c-row reads + per-lane sat nibble byte, 4-deep ILP.
// BRANCHLESS scatter: clamp the word index and ALWAYS atomicOr; value is 0
// for out-of-range/unsat lanes (OR 0 = no-op). No exec manipulation.
__global__ __launch_bounds__(1024) void bitmap_k(const int* __restrict__ adj_pos,
                                                 const int* __restrict__ adj_neg,
                                                 const uint8_t* __restrict__ satp,
                                                 const uint8_t* __restrict__ satn,
                                                 const uint32_t* __restrict__ xbw,
                                                 uint32_t* __restrict__ regions,
                                                 int ne_p, int ne_n) {
    __shared__ uint32_t bm[LDSW];   // 125,056 B
    const int tid = threadIdx.x;
    for (int i = tid; i < LDSW; i += 1024) bm[i] = 0u;
    __syncthreads();

    const int h = blockIdx.x & 1;
    const uint32_t base = (uint32_t)(h * HALF);
    const int w = (blockIdx.x >> 1) * 1024 + tid;   // worker id within half
    const int W = NBH * 1024;                       // 131,072 workers per half

    const int* adjs[2] = {adj_pos, adj_neg};
    const uint8_t* sats[2] = {satp, satn};
    int nes[2] = {ne_p, ne_n};
    for (int pol = 0; pol < 2; ++pol) {
        const int* adj = adjs[pol];
        const uint8_t* sat = sats[pol];
        const int ne = nes[pol];
        const int n4c = ((ne & 3) == 0) ? ((ne & ~255) >> 2) : 0;  // match satv_k
        const int4v* c4p = (const int4v*)adj;

        auto emit = [&](int4v c, uint32_t s) {
            #pragma unroll
            for (int k = 0; k < 4; ++k) {
                uint32_t idx = (uint32_t)c[k] - base;
                uint32_t inr = (idx < (uint32_t)HALF) ? 1u : 0u;
                uint32_t wd = min(idx >> 5, (uint32_t)(WPH - 1));
                uint32_t val = ((s >> k) & inr & 1u) << (idx & 31);
                atomicOr(&bm[wd], val);
            }
        };

        int i = w;
        for (; i + 3 * W < n4c; i += 4 * W) {   // 4-deep ILP, coalesced
            int4v c0 = c4p[i], c1 = c4p[i + W];
            int4v c2 = c4p[i + 2 * W], c3 = c4p[i + 3 * W];
            uint32_t s0 = sat[i],         s1 = sat[i + W];
            uint32_t s2 = sat[i + 2 * W], s3 = sat[i + 3 * W];
            emit(c0, s0); emit(c1, s1); emit(c2, s2); emit(c3, s3);
        }
        for (; i + W < n4c; i += 2 * W) {       // 2-deep drain
            int4v c0 = c4p[i], c1 = c4p[i + W];
            uint32_t s0 = sat[i], s1 = sat[i + W];
            emit(c0, s0); emit(c1, s1);
        }
        for (; i < n4c; i += W) {               // 1-deep drain
            emit(c4p[i], (uint32_t)sat[i]);
        }
        // Tail edges not covered by sat bytes: direct gather (<=255/pol, tiny).
        for (int e = (n4c << 2) + w; e < ne; e += W) {
            uint32_t idx = (uint32_t)adj[e] - base;
            if (idx < (uint32_t)HALF) {
                int vv = adj[ne + e];
                int bit = (int)((xbw[vv >> 5] >> (vv & 31)) & 1u);
                if (bit != pol) atomicOr(&bm[idx >> 5], 1u << (idx & 31));
            }
        }
    }
    __syncthreads();

    // Dense flush (nt -> straight to HBM, full lines; bitmaps re-read once).
    int4v* dst = (int4v*)(regions + (size_t)blockIdx.x * LDSW);
    const int4v* src = (const int4v*)bm;
    for (int i = tid; i < LDSW / 4; i += 1024)
        __builtin_nontemporal_store(src[i], dst + i);
}

// OR the 128 bitmaps of each half per word; a 0 bit anywhere => some clause
// has zero satisfied literals => min == 0.
__global__ __launch_bounds__(256) void reduce_k(const uint32_t* __restrict__ regions,
                                                int* __restrict__ zero_found) {
    int gw = blockIdx.x * 256 + threadIdx.x;   // [0, 2*WPH)
    if (gw >= 2 * WPH) return;
    int h = (gw >= WPH) ? 1 : 0;
    int wd = gw - h * WPH;
    const uint32_t* p = regions + (size_t)h * LDSW + wd;   // region id = 2r+h
    uint32_t o0 = 0, o1 = 0, o2 = 0, o3 = 0;
    for (int r = 0; r < NBH; r += 4) {
        o0 |= p[(size_t)(r + 0) * 2 * LDSW];
        o1 |= p[(size_t)(r + 1) * 2 * LDSW];
        o2 |= p[(size_t)(r + 2) * 2 * LDSW];
        o3 |= p[(size_t)(r + 3) * 2 * LDSW];
    }
    uint32_t acc = (o0 | o1) | (o2 | o3);
    if (acc != 0xFFFFFFFFu) atomicOr(zero_found, 1);
}

// ---- exact-count path (launched every call; early-exits when zero_found) ----
__global__ __launch_bounds__(256) void fbz_k(uint32_t* __restrict__ counts,
                                             const int* __restrict__ zf) {
    if (*zf) return;
    int stride = gridDim.x * blockDim.x;
    for (int i = blockIdx.x * blockDim.x + threadIdx.x; i < NC; i += stride)
        counts[i] = 0u;
}

// Both polarities in one launch (one fewer gated stub).
__global__ __launch_bounds__(256) void fb_edges_k(const int* __restrict__ adj_pos,
                                                  const int* __restrict__ adj_neg,
                                                  const uint32_t* __restrict__ xbw,
                                                  uint32_t* __restrict__ counts,
                                                  int ne_p, int ne_n,
                                                  const int* __restrict__ zf) {
    if (*zf) return;
    int stride = gridDim.x * blockDim.x;
    int i0 = blockIdx.x * blockDim.x + threadIdx.x;
    for (int e = i0; e < ne_p; e += stride) {
        int c = adj_pos[e];
        int v = adj_pos[ne_p + e];
        int bit = (int)((xbw[v >> 5] >> (v & 31)) & 1u);
        if (bit != 0) atomicAdd(&counts[c], 1u);
    }
    for (int e = i0; e < ne_n; e += stride) {
        int c = adj_neg[e];
        int v = adj_neg[ne_n + e];
        int bit = (int)((xbw[v >> 5] >> (v & 31)) & 1u);
        if (bit == 0) atomicAdd(&counts[c], 1u);
    }
}

__global__ __launch_bounds__(256) void fb_min_k(const uint32_t* __restrict__ counts,
                                                int* __restrict__ minslot,
                                                const int* __restrict__ zf) {
    if (*zf) return;
    int stride = gridDim.x * blockDim.x;
    int i0 = blockIdx.x * blockDim.x + threadIdx.x;
    int lo = INT_MAX;
    for (int i = i0; i < NC; i += stride) lo = min(lo, (int)counts[i]);
    for (int off = 32; off > 0; off >>= 1) lo = min(lo, __shfl_down(lo, off));
    if ((threadIdx.x & 63) == 0) atomicMin(minslot, lo);
}

__global__ void fin_k(const int* __restrict__ ctrl, float* __restrict__ out) {
    out[0] = ctrl[0] ? 0.0f : (float)ctrl[1];
}

extern "C" void kernel_launch(void* const* d_in, const int* in_sizes, int n_in,
                              void* d_out, int out_size, void* d_ws, size_t ws_size,
                              hipStream_t stream) {
    const float* xv    = (const float*)d_in[0];
    const int* adj_pos = (const int*)d_in[1];   // int32 per harness contract
    const int* adj_neg = (const int*)d_in[2];
    float* out = (float*)d_out;

    const int nv   = in_sizes[0];
    const int ne_p = in_sizes[1] / 2;   // rows: [clause, var]
    const int ne_n = in_sizes[2] / 2;

    char* ws = (char*)d_ws;
    dim3 blk(256);

    const size_t xbb_by   = (((size_t)nv + 7) / 8 + 64) & ~63ull;
    const size_t satp_by  = (((size_t)(ne_p & ~255) / 4) + 63) & ~63ull;  // u8/int4-group
    const size_t satn_by  = (((size_t)(ne_n & ~255) / 4) + 63) & ~63ull;
    const size_t off_satp = OFF_XBB + xbb_by;
    const size_t off_satn = off_satp + satp_by;
    const size_t off_ctl  = off_satn + satn_by;
    const size_t need     = off_ctl + 64;          // ~36.27 MB at reference sizes

    if (ws_size >= need && nv == NV) {
        uint32_t* rgn  = (uint32_t*)(ws + OFF_BM);
        uint32_t* cnts = (uint32_t*)(ws + OFF_CNT);   // aliases rgn (dead after reduce)
        uint8_t*  xbb  = (uint8_t*) (ws + OFF_XBB);
        uint8_t*  satp = (uint8_t*) (ws + off_satp);
        uint8_t*  satn = (uint8_t*) (ws + off_satn);
        int*      ctrl = (int*)     (ws + off_ctl);   // [0]=zero_found [1]=minslot
        const uint32_t* xbw = (const uint32_t*)xbb;

        init_k<<<512, blk, 0, stream>>>(xv, nv, xbb, ctrl);
        satv_k<<<256, dim3(1024), 0, stream>>>(adj_pos, adj_neg, xbw,
                                               satp, satn, ne_p, ne_n);
        bitmap_k<<<NBLK, dim3(1024), 0, stream>>>(adj_pos, adj_neg, satp, satn,
                                                  xbw, rgn, ne_p, ne_n);
        reduce_k<<<(2 * WPH + 255) / 256, blk, 0, stream>>>(rgn, ctrl);
        // Exact path: launched every call, early-exits when a zero clause exists.
        fbz_k<<<2048, blk, 0, stream>>>(cnts, ctrl);
        fb_edges_k<<<2048, blk, 0, stream>>>(adj_pos, adj_neg, xbw, cnts,
                                             ne_p, ne_n, ctrl);
        fb_min_k<<<2048, blk, 0, stream>>>(cnts, ctrl + 1, ctrl);
        fin_k<<<1, 1, 0, stream>>>(ctrl, out);
    } else {
        // Minimal-ws fallback: exact path only (ungated).
        const size_t cnt_by = (size_t)NC * 4;
        uint32_t* cnts = (uint32_t*)ws;
        uint8_t*  xbb  = (uint8_t*) (ws + cnt_by);
        int*      ctrl = (int*)     (ws + cnt_by + xbb_by);
        const uint32_t* xbw = (const uint32_t*)xbb;
        init_k<<<512, blk, 0, stream>>>(xv, nv, xbb, ctrl);
        fbz_k<<<2048, blk, 0, stream>>>(cnts, ctrl);            // ctrl[0]==0 -> runs
        fb_edges_k<<<2048, blk, 0, stream>>>(adj_pos, adj_neg, xbw, cnts,
                                             ne_p, ne_n, ctrl);
        fb_min_k<<<2048, blk, 0, stream>>>(cnts, ctrl + 1, ctrl);
        fin_k<<<1, 1, 0, stream>>>(ctrl, out);
    }
}

// Round 18
// 88.646 us; speedup vs baseline: 1.3927x; 1.3927x over previous
//
#include <hip/hip_runtime.h>
#include <cstdint>
#include <climits>

static constexpr int NC    = 2000000;         // clause id range (fixed by reference)
static constexpr int HALF  = 1000000;         // clauses per half-range
static constexpr int NV    = 2000000;         // variables (fixed by reference)
static constexpr int HALFV = 1000000;         // vars per half
static constexpr int NBH   = 128;             // bitmap blocks per clause half
static constexpr int NBLK  = 2 * NBH;         // 256 bitmap blocks (1 per CU)
static constexpr int WPH   = HALF / 32;       // 31,250 words per clause bitmap
static constexpr int WPHV  = HALFV / 32;      // 31,250 words per var bitmap half
static constexpr int LDSW  = 31264;           // LDS alloc words (pad to /4)
static_assert(HALF % 32 == 0 && LDSW % 4 == 0 && LDSW >= WPH && LDSW >= WPHV, "layout");

typedef int   int4v   __attribute__((ext_vector_type(4)));
typedef float float4v __attribute__((ext_vector_type(4)));

// ws layout (bytes). counts[] for the exact path ALIASES the bitmap region
// (bitmaps are dead after reduce_k; stream order serializes the reuse).
static constexpr size_t OFF_BM  = 0;
static constexpr size_t BM_BY   = (size_t)NBLK * LDSW * 4;   // 32,014,336 (64-aligned)
static constexpr size_t OFF_CNT = 0;                          // alias (8 MB)
static constexpr size_t OFF_XBB = BM_BY;                      // bit-packed xb

// Pack xb bits (xb = floor(xv/0.50001f), true f32 divide to match reference),
// init ctrl.
__global__ __launch_bounds__(256) void init_k(const float* __restrict__ xv, int nv,
                                              uint8_t* __restrict__ xbb,
                                              int* __restrict__ ctrl) {
    int stride = gridDim.x * blockDim.x;
    int i0 = blockIdx.x * blockDim.x + threadIdx.x;
    int nbytes = nv >> 3;
    const float4v* p4 = (const float4v*)xv;
    for (int i = i0; i < nbytes; i += stride) {
        float4v a = p4[2 * i], b = p4[2 * i + 1];
        uint32_t m = 0;
        #pragma unroll
        for (int j = 0; j < 4; ++j)
            m |= ((uint32_t)(int)floorf(a[j] / 0.50001f)) << j;
        #pragma unroll
        for (int j = 0; j < 4; ++j)
            m |= ((uint32_t)(int)floorf(b[j] / 0.50001f)) << (4 + j);
        xbb[i] = (uint8_t)m;
    }
    if (i0 == 0) {
        if (nv & 7) {
            uint32_t m = 0;
            for (int j = 0; j < (nv & 7); ++j)
                m |= ((uint32_t)(int)floorf(xv[(nbytes << 3) + j] / 0.50001f)) << j;
            xbb[nbytes] = (uint8_t)m;
        }
        ctrl[0] = 0;        // zero_found
        ctrl[1] = INT_MAX;  // minslot (exact path)
    }
}

// Sat pass with LDS-resident var bitmap (round-16 version — measured 38.8 us,
// at the mixed L3/HBM BW floor: 128 MB v-rows + 8 MB sat at ~3.4 TB/s).
// NIBBLE-BYTE output: one coalesced plain byte per lane, no shfl.
// hv=0 overwrites, hv=1 same-thread ORs. Coverage = ne & ~255.
__global__ __launch_bounds__(1024) void satv_k(const int* __restrict__ adj_pos,
                                               const int* __restrict__ adj_neg,
                                               const uint32_t* __restrict__ xbw,
                                               uint8_t* __restrict__ satp,
                                               uint8_t* __restrict__ satn,
                                               int ne_p, int ne_n) {
    __shared__ uint32_t vbm[LDSW];
    const int tid = threadIdx.x;
    const int w0 = blockIdx.x * 1024 + tid;
    const int W = gridDim.x * 1024;          // 262,144 workers

    const int* adjs[2] = {adj_pos, adj_neg};
    uint8_t* sats[2] = {satp, satn};
    int nes[2] = {ne_p, ne_n};

    for (int hv = 0; hv < 2; ++hv) {
        const uint32_t* src = xbw + hv * WPHV;
        for (int j = tid; j < WPHV; j += 1024) vbm[j] = src[j];
        __syncthreads();
        const uint32_t vbase = (uint32_t)(hv * HALFV);

        for (int pol = 0; pol < 2; ++pol) {
            const int ne = nes[pol];
            const int n4c = ((ne & 3) == 0) ? ((ne & ~255) >> 2) : 0;
            const int4v* v4p = (const int4v*)(adjs[pol] + ne);
            uint8_t* sat = sats[pol];

            auto nib = [&](int4v va) -> uint32_t {
                uint32_t n = 0;
                #pragma unroll
                for (int k = 0; k < 4; ++k) {
                    uint32_t u = (uint32_t)va[k] - vbase;
                    if (u < (uint32_t)HALFV) {
                        uint32_t bit = (vbm[u >> 5] >> (u & 31)) & 1u;
                        n |= (pol ? (bit ^ 1u) : bit) << k;
                    }
                }
                return n;
            };

            int i = w0;
            if (hv == 0) {
                for (; i + W < n4c; i += 2 * W) {        // 2-deep ILP
                    int4v v0 = v4p[i], v1 = v4p[i + W];
                    uint32_t n0 = nib(v0), n1 = nib(v1);
                    sat[i] = (uint8_t)n0;
                    sat[i + W] = (uint8_t)n1;
                }
                for (; i < n4c; i += W) sat[i] = (uint8_t)nib(v4p[i]);
            } else {
                for (; i + W < n4c; i += 2 * W) {
                    int4v v0 = v4p[i], v1 = v4p[i + W];
                    uint32_t n0 = nib(v0), n1 = nib(v1);
                    sat[i] |= (uint8_t)n0;
                    sat[i + W] |= (uint8_t)n1;
                }
                for (; i < n4c; i += W) sat[i] |= (uint8_t)nib(v4p[i]);
            }
        }
        __syncthreads();   // drain vbm readers before reloading half B
    }
}

// Bitmap pass (round-16 version — predicated emit; round-17's branchless
// always-atomicOr clamped 50% of lanes onto ONE word -> same-address LDS
// atomic serialization, 15.5M conflict cycles, +34 us. Predication is
// cheaper than a serialized dump target). 4-deep ILP, coalesced c-reads.
// Flush uses PLAIN stores so lines land L3-resident for reduce_k.
__global__ __launch_bounds__(1024) void bitmap_k(const int* __restrict__ adj_pos,
                                                 const int* __restrict__ adj_neg,
                                                 const uint8_t* __restrict__ satp,
                                                 const uint8_t* __restrict__ satn,
                                                 const uint32_t* __restrict__ xbw,
                                                 uint32_t* __restrict__ regions,
                                                 int ne_p, int ne_n) {
    __shared__ uint32_t bm[LDSW];   // 125,056 B
    const int tid = threadIdx.x;
    for (int i = tid; i < LDSW; i += 1024) bm[i] = 0u;
    __syncthreads();

    const int h = blockIdx.x & 1;
    const uint32_t base = (uint32_t)(h * HALF);
    const int w = (blockIdx.x >> 1) * 1024 + tid;   // worker id within half
    const int W = NBH * 1024;                       // 131,072 workers per half

    const int* adjs[2] = {adj_pos, adj_neg};
    const uint8_t* sats[2] = {satp, satn};
    int nes[2] = {ne_p, ne_n};
    for (int pol = 0; pol < 2; ++pol) {
        const int* adj = adjs[pol];
        const uint8_t* sat = sats[pol];
        const int ne = nes[pol];
        const int n4c = ((ne & 3) == 0) ? ((ne & ~255) >> 2) : 0;  // match satv_k
        const int4v* c4p = (const int4v*)adj;

        auto emit = [&](int4v c, uint32_t s) {
            #pragma unroll
            for (int k = 0; k < 4; ++k) {
                uint32_t idx = (uint32_t)c[k] - base;
                if (idx < (uint32_t)HALF && ((s >> k) & 1u))
                    atomicOr(&bm[idx >> 5], 1u << (idx & 31));
            }
        };

        int i = w;
        for (; i + 3 * W < n4c; i += 4 * W) {   // 4-deep ILP, coalesced
            int4v c0 = c4p[i], c1 = c4p[i + W];
            int4v c2 = c4p[i + 2 * W], c3 = c4p[i + 3 * W];
            uint32_t s0 = sat[i],         s1 = sat[i + W];
            uint32_t s2 = sat[i + 2 * W], s3 = sat[i + 3 * W];
            emit(c0, s0); emit(c1, s1); emit(c2, s2); emit(c3, s3);
        }
        for (; i + W < n4c; i += 2 * W) {       // 2-deep drain
            int4v c0 = c4p[i], c1 = c4p[i + W];
            uint32_t s0 = sat[i], s1 = sat[i + W];
            emit(c0, s0); emit(c1, s1);
        }
        for (; i < n4c; i += W) {               // 1-deep drain
            emit(c4p[i], (uint32_t)sat[i]);
        }
        // Tail edges not covered by sat bytes: direct gather (<=255/pol, tiny).
        for (int e = (n4c << 2) + w; e < ne; e += W) {
            uint32_t idx = (uint32_t)adj[e] - base;
            if (idx < (uint32_t)HALF) {
                int vv = adj[ne + e];
                int bit = (int)((xbw[vv >> 5] >> (vv & 31)) & 1u);
                if (bit != pol) atomicOr(&bm[idx >> 5], 1u << (idx & 31));
            }
        }
    }
    __syncthreads();

    // Dense flush (plain stores -> L3-resident for reduce_k's re-read).
    int4v* dst = (int4v*)(regions + (size_t)blockIdx.x * LDSW);
    const int4v* src = (const int4v*)bm;
    for (int i = tid; i < LDSW / 4; i += 1024)
        dst[i] = src[i];
}

// OR the 128 bitmaps of each half per word; a 0 bit anywhere => some clause
// has zero satisfied literals => min == 0.
__global__ __launch_bounds__(256) void reduce_k(const uint32_t* __restrict__ regions,
                                                int* __restrict__ zero_found) {
    int gw = blockIdx.x * 256 + threadIdx.x;   // [0, 2*WPH)
    if (gw >= 2 * WPH) return;
    int h = (gw >= WPH) ? 1 : 0;
    int wd = gw - h * WPH;
    const uint32_t* p = regions + (size_t)h * LDSW + wd;   // region id = 2r+h
    uint32_t o0 = 0, o1 = 0, o2 = 0, o3 = 0;
    for (int r = 0; r < NBH; r += 4) {
        o0 |= p[(size_t)(r + 0) * 2 * LDSW];
        o1 |= p[(size_t)(r + 1) * 2 * LDSW];
        o2 |= p[(size_t)(r + 2) * 2 * LDSW];
        o3 |= p[(size_t)(r + 3) * 2 * LDSW];
    }
    uint32_t acc = (o0 | o1) | (o2 | o3);
    if (acc != 0xFFFFFFFFu) atomicOr(zero_found, 1);
}

// ---- exact-count path (launched every call; early-exits when zero_found) ----
__global__ __launch_bounds__(256) void fbz_k(uint32_t* __restrict__ counts,
                                             const int* __restrict__ zf) {
    if (*zf) return;
    int stride = gridDim.x * blockDim.x;
    for (int i = blockIdx.x * blockDim.x + threadIdx.x; i < NC; i += stride)
        counts[i] = 0u;
}

// Both polarities in one launch (one fewer gated stub).
__global__ __launch_bounds__(256) void fb_edges_k(const int* __restrict__ adj_pos,
                                                  const int* __restrict__ adj_neg,
                                                  const uint32_t* __restrict__ xbw,
                                                  uint32_t* __restrict__ counts,
                                                  int ne_p, int ne_n,
                                                  const int* __restrict__ zf) {
    if (*zf) return;
    int stride = gridDim.x * blockDim.x;
    int i0 = blockIdx.x * blockDim.x + threadIdx.x;
    for (int e = i0; e < ne_p; e += stride) {
        int c = adj_pos[e];
        int v = adj_pos[ne_p + e];
        int bit = (int)((xbw[v >> 5] >> (v & 31)) & 1u);
        if (bit != 0) atomicAdd(&counts[c], 1u);
    }
    for (int e = i0; e < ne_n; e += stride) {
        int c = adj_neg[e];
        int v = adj_neg[ne_n + e];
        int bit = (int)((xbw[v >> 5] >> (v & 31)) & 1u);
        if (bit == 0) atomicAdd(&counts[c], 1u);
    }
}

__global__ __launch_bounds__(256) void fb_min_k(const uint32_t* __restrict__ counts,
                                                int* __restrict__ minslot,
                                                const int* __restrict__ zf) {
    if (*zf) return;
    int stride = gridDim.x * blockDim.x;
    int i0 = blockIdx.x * blockDim.x + threadIdx.x;
    int lo = INT_MAX;
    for (int i = i0; i < NC; i += stride) lo = min(lo, (int)counts[i]);
    for (int off = 32; off > 0; off >>= 1) lo = min(lo, __shfl_down(lo, off));
    if ((threadIdx.x & 63) == 0) atomicMin(minslot, lo);
}

__global__ void fin_k(const int* __restrict__ ctrl, float* __restrict__ out) {
    out[0] = ctrl[0] ? 0.0f : (float)ctrl[1];
}

extern "C" void kernel_launch(void* const* d_in, const int* in_sizes, int n_in,
                              void* d_out, int out_size, void* d_ws, size_t ws_size,
                              hipStream_t stream) {
    const float* xv    = (const float*)d_in[0];
    const int* adj_pos = (const int*)d_in[1];   // int32 per harness contract
    const int* adj_neg = (const int*)d_in[2];
    float* out = (float*)d_out;

    const int nv   = in_sizes[0];
    const int ne_p = in_sizes[1] / 2;   // rows: [clause, var]
    const int ne_n = in_sizes[2] / 2;

    char* ws = (char*)d_ws;
    dim3 blk(256);

    const size_t xbb_by   = (((size_t)nv + 7) / 8 + 64) & ~63ull;
    const size_t satp_by  = (((size_t)(ne_p & ~255) / 4) + 63) & ~63ull;  // u8/int4-group
    const size_t satn_by  = (((size_t)(ne_n & ~255) / 4) + 63) & ~63ull;
    const size_t off_satp = OFF_XBB + xbb_by;
    const size_t off_satn = off_satp + satp_by;
    const size_t off_ctl  = off_satn + satn_by;
    const size_t need     = off_ctl + 64;          // ~36.27 MB at reference sizes

    if (ws_size >= need && nv == NV) {
        uint32_t* rgn  = (uint32_t*)(ws + OFF_BM);
        uint32_t* cnts = (uint32_t*)(ws + OFF_CNT);   // aliases rgn (dead after reduce)
        uint8_t*  xbb  = (uint8_t*) (ws + OFF_XBB);
        uint8_t*  satp = (uint8_t*) (ws + off_satp);
        uint8_t*  satn = (uint8_t*) (ws + off_satn);
        int*      ctrl = (int*)     (ws + off_ctl);   // [0]=zero_found [1]=minslot
        const uint32_t* xbw = (const uint32_t*)xbb;

        init_k<<<1024, blk, 0, stream>>>(xv, nv, xbb, ctrl);
        satv_k<<<256, dim3(1024), 0, stream>>>(adj_pos, adj_neg, xbw,
                                               satp, satn, ne_p, ne_n);
        bitmap_k<<<NBLK, dim3(1024), 0, stream>>>(adj_pos, adj_neg, satp, satn,
                                                  xbw, rgn, ne_p, ne_n);
        reduce_k<<<(2 * WPH + 255) / 256, blk, 0, stream>>>(rgn, ctrl);
        // Exact path: launched every call, early-exits when a zero clause exists.
        fbz_k<<<1024, blk, 0, stream>>>(cnts, ctrl);
        fb_edges_k<<<1024, blk, 0, stream>>>(adj_pos, adj_neg, xbw, cnts,
                                             ne_p, ne_n, ctrl);
        fb_min_k<<<1024, blk, 0, stream>>>(cnts, ctrl + 1, ctrl);
        fin_k<<<1, 1, 0, stream>>>(ctrl, out);
    } else {
        // Minimal-ws fallback: exact path only (ungated).
        const size_t cnt_by = (size_t)NC * 4;
        uint32_t* cnts = (uint32_t*)ws;
        uint8_t*  xbb  = (uint8_t*) (ws + cnt_by);
        int*      ctrl = (int*)     (ws + cnt_by + xbb_by);
        const uint32_t* xbw = (const uint32_t*)xbb;
        init_k<<<1024, blk, 0, stream>>>(xv, nv, xbb, ctrl);
        fbz_k<<<2048, blk, 0, stream>>>(cnts, ctrl);            // ctrl[0]==0 -> runs
        fb_edges_k<<<2048, blk, 0, stream>>>(adj_pos, adj_neg, xbw, cnts,
                                             ne_p, ne_n, ctrl);
        fb_min_k<<<2048, blk, 0, stream>>>(cnts, ctrl + 1, ctrl);
        fin_k<<<1, 1, 0, stream>>>(ctrl, out);
    }
}